// Round 1
// baseline (162.550 us; speedup 1.0000x reference)
//
#include <hip/hip_runtime.h>

// HaloAttention with the lucidrains masking bug faithfully replicated:
// in-bounds keys are masked to -FLT_MAX, so
//   * interior blocks  -> uniform attention = box-mean of v over the 16x16 window
//   * border blocks    -> attention only on zero-padded keys, v=0 there -> output exactly 0
// Collapse: out_block = mean_{16x16}(x) @ (w_kv[:,512:] @ w_out) + b_out  (interior),
//           out_block = 0 (border). q, rel_height, rel_width, w_q are dead inputs.

#define C_DIM 256

// W[c][c2] = sum_{j=0..511} w_kv[c][512+j] * w_out[j][c2]
__global__ __launch_bounds__(256)
void compose_W_kernel(const float* __restrict__ w_kv,
                      const float* __restrict__ w_out,
                      float* __restrict__ W) {
    const int c  = blockIdx.x;    // 0..255 (input channel)
    const int c2 = threadIdx.x;   // 0..255 (output channel)
    const float* kvrow = w_kv + (size_t)c * 1024 + 512;  // v-half of row c
    float acc = 0.f;
#pragma unroll 8
    for (int j = 0; j < 512; ++j) {
        acc = fmaf(kvrow[j], w_out[(size_t)j * 256 + c2], acc);
    }
    W[(size_t)c * 256 + c2] = acc;
}

__global__ __launch_bounds__(256)
void halo_collapsed_kernel(const float* __restrict__ x,
                           const float* __restrict__ W,
                           const float* __restrict__ b_out,
                           float* __restrict__ out) {
    const int blk = blockIdx.x;   // 0..63 spatial block
    const int b   = blockIdx.y;   // batch 0..7
    const int bi  = blk >> 3;
    const int bj  = blk & 7;
    const int c   = threadIdx.x;  // channel 0..255

    const size_t plane = ((size_t)b * C_DIM + (size_t)c) * 4096;  // [b, c, 64, 64]
    const bool interior = (bi >= 1) & (bi <= 6) & (bj >= 1) & (bj <= 6);

    __shared__ float meanrow[C_DIM];
    float val = 0.f;

    if (interior) {
        const int r0 = bi * 8 - 4;          // window top row (in-bounds for interior)
        const int c0 = bj * 8 - 4;          // window left col, multiple of 4 -> float4 ok
        const float* xb = x + plane + (size_t)r0 * 64 + c0;
        float s = 0.f;
#pragma unroll
        for (int r = 0; r < 16; ++r) {
            const float4* row4 = (const float4*)(xb + (size_t)r * 64);
            float4 a0 = row4[0], a1 = row4[1], a2 = row4[2], a3 = row4[3];
            s += (a0.x + a0.y + a0.z + a0.w)
               + (a1.x + a1.y + a1.z + a1.w)
               + (a2.x + a2.y + a2.z + a2.w)
               + (a3.x + a3.y + a3.z + a3.w);
        }
        meanrow[c] = s * (1.f / 256.f);
    }
    __syncthreads();  // branch is uniform per block (depends only on blockIdx)

    if (interior) {
        float acc = b_out[c];
#pragma unroll 8
        for (int k = 0; k < 256; ++k) {
            acc = fmaf(meanrow[k], W[(size_t)k * 256 + c], acc);  // coalesced over c
        }
        val = acc;
    }

    // broadcast to the 8x8 output block for this channel (covers ALL pixels,
    // border blocks get exact zeros -> no memset needed)
    float* obase = out + plane + (size_t)(bi * 8) * 64 + (size_t)(bj * 8);
    const float4 v4 = make_float4(val, val, val, val);
#pragma unroll
    for (int r = 0; r < 8; ++r) {
        ((float4*)(obase + (size_t)r * 64))[0] = v4;
        ((float4*)(obase + (size_t)r * 64 + 4))[0] = v4;
    }
}

extern "C" void kernel_launch(void* const* d_in, const int* in_sizes, int n_in,
                              void* d_out, int out_size, void* d_ws, size_t ws_size,
                              hipStream_t stream) {
    // setup_inputs order: x, w_q, w_kv, w_out, b_out, rel_height, rel_width
    const float* x     = (const float*)d_in[0];
    const float* w_kv  = (const float*)d_in[2];
    const float* w_out = (const float*)d_in[3];
    const float* b_out = (const float*)d_in[4];
    float* W = (float*)d_ws;  // 256*256 floats = 256 KiB scratch

    compose_W_kernel<<<256, 256, 0, stream>>>(w_kv, w_out, W);
    halo_collapsed_kernel<<<dim3(64, 8), 256, 0, stream>>>(x, W, b_out, (float*)d_out);
}

// Round 2
// 127.362 us; speedup vs baseline: 1.2763x; 1.2763x over previous
//
#include <hip/hip_runtime.h>

// HaloAttention with the lucidrains masking bug faithfully replicated:
// in-bounds keys get -FLT_MAX, so
//   * interior blocks -> uniform attention = 16x16 box-mean of v
//   * border blocks   -> attention only on zero-padded keys -> output exactly 0
// Collapse: out_block = mean16x16(x) @ (w_kv[:,512:] @ w_out) + b_out (interior),
//           0 (border). q / w_q / rel_* are dead inputs.
//
// Dispatch 1 (prep): blocks 0..2047 compute per-(b,c) window means reading x
//   exactly once (coalesced, via 4x4 coarse-tile sums; windows start at
//   multiples of 4). Blocks 2048..2175 compose W = w_kv_v @ w_out (2 rows/wg).
// Dispatch 2 (out): per (b, spatial block): means-row @ W + b_out, broadcast
//   to the 8x8 block; border blocks write exact zeros.

__global__ __launch_bounds__(256)
void halo_prep_kernel(const float* __restrict__ x,
                      const float* __restrict__ w_kv,
                      const float* __restrict__ w_out,
                      float* __restrict__ W,
                      float* __restrict__ means) {
    const int t = threadIdx.x;
    if (blockIdx.x < 2048) {
        // ---- window means for one (b, c) plane ----
        const int b = blockIdx.x >> 8;
        const int c = blockIdx.x & 255;
        const float* plane = x + ((size_t)b * 256 + c) * 4096;  // [64,64]
        __shared__ float ts[256];  // 16x16 coarse 4x4-tile sums
        const int ti = t >> 4, tj = t & 15;
        const float* tp = plane + (size_t)(ti * 4) * 64 + tj * 4;
        float s = 0.f;
#pragma unroll
        for (int r = 0; r < 4; ++r) {
            float4 a = *(const float4*)(tp + (size_t)r * 64);
            s += (a.x + a.y) + (a.z + a.w);
        }
        ts[t] = s;
        __syncthreads();
        if (t < 36) {
            // interior block (bi,bj) = (wi+1, wj+1); window top-left row
            // bi*8-4 -> tile row 2*bi-1, spans 4 tile rows/cols
            const int wi = t / 6, wj = t - wi * 6;
            const int tr = 2 * wi + 1, tc = 2 * wj + 1;
            float acc = 0.f;
#pragma unroll
            for (int di = 0; di < 4; ++di)
#pragma unroll
                for (int dj = 0; dj < 4; ++dj)
                    acc += ts[(tr + di) * 16 + (tc + dj)];
            means[((size_t)b * 36 + t) * 256 + c] = acc * (1.f / 256.f);
        }
    } else {
        // ---- compose W rows c0, c0+1: W[c][c2] = sum_j w_kv[c][512+j]*w_out[j][c2] ----
        const int c0 = (blockIdx.x - 2048) * 2;
        const float* kv0 = w_kv + (size_t)c0 * 1024 + 512;
        const float* kv1 = kv0 + 1024;
        float a0 = 0.f, a1 = 0.f;
#pragma unroll 8
        for (int j = 0; j < 512; ++j) {
            const float wo = w_out[(size_t)j * 256 + t];  // coalesced over t
            a0 = fmaf(kv0[j], wo, a0);                    // kv*: wg-uniform scalar loads
            a1 = fmaf(kv1[j], wo, a1);
        }
        W[(size_t)c0 * 256 + t] = a0;
        W[((size_t)c0 + 1) * 256 + t] = a1;
    }
}

__global__ __launch_bounds__(256)
void halo_out_kernel(const float* __restrict__ W,
                     const float* __restrict__ means,
                     const float* __restrict__ b_out,
                     float* __restrict__ out) {
    const int blk = blockIdx.x;   // 0..63 spatial block
    const int b   = blockIdx.y;   // batch
    const int bi  = blk >> 3, bj = blk & 7;
    const int c   = threadIdx.x;  // output channel
    const bool interior = (bi >= 1) & (bi <= 6) & (bj >= 1) & (bj <= 6);

    float val = 0.f;
    __shared__ float m[256];
    if (interior) {  // wg-uniform branch -> barrier inside is legal
        const int w = (bi - 1) * 6 + (bj - 1);
        m[c] = means[((size_t)b * 36 + w) * 256 + c];
        __syncthreads();
        float acc0 = b_out[c], acc1 = 0.f, acc2 = 0.f, acc3 = 0.f;
#pragma unroll 4
        for (int k = 0; k < 256; k += 4) {  // W reads coalesced over c, L2-resident
            acc0 = fmaf(m[k],     W[(size_t)(k)     * 256 + c], acc0);
            acc1 = fmaf(m[k + 1], W[(size_t)(k + 1) * 256 + c], acc1);
            acc2 = fmaf(m[k + 2], W[(size_t)(k + 2) * 256 + c], acc2);
            acc3 = fmaf(m[k + 3], W[(size_t)(k + 3) * 256 + c], acc3);
        }
        val = (acc0 + acc1) + (acc2 + acc3);
    }

    float* ob = out + ((size_t)b * 256 + c) * 4096 + (size_t)(bi * 8) * 64 + bj * 8;
    const float4 v4 = make_float4(val, val, val, val);
#pragma unroll
    for (int r = 0; r < 8; ++r) {
        *(float4*)(ob + (size_t)r * 64)     = v4;
        *(float4*)(ob + (size_t)r * 64 + 4) = v4;
    }
}

extern "C" void kernel_launch(void* const* d_in, const int* in_sizes, int n_in,
                              void* d_out, int out_size, void* d_ws, size_t ws_size,
                              hipStream_t stream) {
    // setup_inputs order: x, w_q, w_kv, w_out, b_out, rel_height, rel_width
    const float* x     = (const float*)d_in[0];
    const float* w_kv  = (const float*)d_in[2];
    const float* w_out = (const float*)d_in[3];
    const float* b_out = (const float*)d_in[4];
    float* W     = (float*)d_ws;            // 256*256 floats = 256 KiB
    float* means = W + 256 * 256;           // 8*36*256 floats = 288 KiB

    halo_prep_kernel<<<2048 + 128, 256, 0, stream>>>(x, w_kv, w_out, W, means);
    halo_out_kernel<<<dim3(64, 8), 256, 0, stream>>>(W, means, b_out, (float*)d_out);
}

// Round 3
// 122.541 us; speedup vs baseline: 1.3265x; 1.0393x over previous
//
#include <hip/hip_runtime.h>

// HaloAttention with the lucidrains masking bug faithfully replicated:
// in-bounds keys get -FLT_MAX, so
//   * interior blocks -> uniform attention = 16x16 box-mean of v
//   * border blocks   -> attention only on zero-padded keys -> output exactly 0
// Collapse: out_block = mean16x16(x) @ (w_kv[:,512:] @ w_out) + b_out (interior),
//           0 (border). q / w_q / rel_* are dead inputs.
//
// Dispatch 1 (prep): blocks 0..2047 compute per-(b,c) 16x16 window means
//   reading x exactly once (coalesced, via 4x4 coarse-tile sums; windows start
//   at multiples of 4). Blocks 2048..2175 compose W = w_kv_v @ w_out.
// Dispatch 2 (out): block = (channel-group g, block-row bi, batch b).
//   Phase 1: matvec outv[bj][c] for bj=0..7 into LDS (borders exact 0).
//   Phase 2: stream the 8-row x 64-col x 32-channel strip with fully
//   coalesced 1 KB-per-wave float4 stores.

__global__ __launch_bounds__(256)
void halo_prep_kernel(const float* __restrict__ x,
                      const float* __restrict__ w_kv,
                      const float* __restrict__ w_out,
                      float* __restrict__ W,
                      float* __restrict__ means) {
    const int t = threadIdx.x;
    if (blockIdx.x < 2048) {
        // ---- window means for one (b, c) plane ----
        const int b = blockIdx.x >> 8;
        const int c = blockIdx.x & 255;
        const float* plane = x + ((size_t)b * 256 + c) * 4096;  // [64,64]
        __shared__ float ts[256];  // 16x16 coarse 4x4-tile sums
        const int ti = t >> 4, tj = t & 15;
        const float* tp = plane + (size_t)(ti * 4) * 64 + tj * 4;
        float s = 0.f;
#pragma unroll
        for (int r = 0; r < 4; ++r) {
            float4 a = *(const float4*)(tp + (size_t)r * 64);
            s += (a.x + a.y) + (a.z + a.w);
        }
        ts[t] = s;
        __syncthreads();
        if (t < 36) {
            // interior block (bi,bj) = (wi+1, wj+1); window top-left row
            // bi*8-4 -> tile row 2*bi-1, spans 4 tile rows/cols
            const int wi = t / 6, wj = t - wi * 6;
            const int tr = 2 * wi + 1, tc = 2 * wj + 1;
            float acc = 0.f;
#pragma unroll
            for (int di = 0; di < 4; ++di)
#pragma unroll
                for (int dj = 0; dj < 4; ++dj)
                    acc += ts[(tr + di) * 16 + (tc + dj)];
            means[((size_t)b * 36 + t) * 256 + c] = acc * (1.f / 256.f);
        }
    } else {
        // ---- compose W rows c0, c0+1: W[c][c2] = sum_j w_kv[c][512+j]*w_out[j][c2] ----
        const int c0 = (blockIdx.x - 2048) * 2;
        const float* kv0 = w_kv + (size_t)c0 * 1024 + 512;
        const float* kv1 = kv0 + 1024;
        float a0 = 0.f, a1 = 0.f;
#pragma unroll 8
        for (int j = 0; j < 512; ++j) {
            const float wo = w_out[(size_t)j * 256 + t];  // coalesced over t
            a0 = fmaf(kv0[j], wo, a0);                    // kv*: wg-uniform scalar loads
            a1 = fmaf(kv1[j], wo, a1);
        }
        W[(size_t)c0 * 256 + t] = a0;
        W[((size_t)c0 + 1) * 256 + t] = a1;
    }
}

__global__ __launch_bounds__(256)
void halo_out_kernel(const float* __restrict__ W,
                     const float* __restrict__ means,
                     const float* __restrict__ b_out,
                     float* __restrict__ out) {
    const int g  = blockIdx.x;   // channel group 0..7 (32 channels)
    const int bi = blockIdx.y;   // block row 0..7
    const int b  = blockIdx.z;   // batch
    const int t  = threadIdx.x;
    const bool bi_int = (bi >= 1) & (bi <= 6);

    __shared__ float m_lds[8][256];   // means rows per bj (0 at border bj)
    __shared__ float outv[32 * 9];    // [c_local][bj], stride 9 kills bank conflicts

    if (bi_int) {  // wg-uniform branch: barriers inside are legal
        // stage means rows (bj=1..6 real, bj=0,7 zero)
        const int row = t >> 5;        // 0..7
        const int col0 = t & 31;
        const float* mrow = (row >= 1 && row <= 6)
            ? &means[((size_t)b * 36 + (size_t)(bi - 1) * 6 + (row - 1)) * 256]
            : nullptr;
#pragma unroll
        for (int kk = col0; kk < 256; kk += 32)
            m_lds[row][kk] = mrow ? mrow[kk] : 0.f;
        __syncthreads();

        // matvec: thread (bj = t>>5, cl = t&31) computes outv[cl][bj]
        const int bj = t >> 5;
        const int cl = t & 31;
        const int c  = g * 32 + cl;
        float a0 = 0.f, a1 = 0.f, a2 = 0.f, a3 = 0.f;
        const float* mr = m_lds[bj];
#pragma unroll 4
        for (int k = 0; k < 256; k += 4) {  // W[k][c]: one hot 128B segment/wave
            a0 = fmaf(mr[k],     W[(size_t)(k)     * 256 + c], a0);
            a1 = fmaf(mr[k + 1], W[(size_t)(k + 1) * 256 + c], a1);
            a2 = fmaf(mr[k + 2], W[(size_t)(k + 2) * 256 + c], a2);
            a3 = fmaf(mr[k + 3], W[(size_t)(k + 3) * 256 + c], a3);
        }
        const float acc = (a0 + a1) + (a2 + a3);
        outv[cl * 9 + bj] = ((bj >= 1) & (bj <= 6)) ? acc + b_out[c] : 0.f;
        __syncthreads();
    }

    // phase 2: stream the strip out[b][g*32..+32][bi*8..+8][0..64]
    // wave writes 1 KB fully contiguous (8 rows x 64 cols = 2 KB per channel)
    float* base = out + ((size_t)(b * 256 + g * 32)) * 4096 + (size_t)(bi * 8) * 64;
#pragma unroll
    for (int i = 0; i < 16; ++i) {
        const int idx = i * 256 + t;     // float4 index in the 64 KB strip
        const int cl2 = idx >> 7;        // 128 float4 per channel
        const int rem = idx & 127;       // y*16 + x4
        const int x4  = rem & 15;
        const float v = bi_int ? outv[cl2 * 9 + (x4 >> 1)] : 0.f;
        *(float4*)(base + (size_t)cl2 * 4096 + (size_t)rem * 4) = make_float4(v, v, v, v);
    }
}

extern "C" void kernel_launch(void* const* d_in, const int* in_sizes, int n_in,
                              void* d_out, int out_size, void* d_ws, size_t ws_size,
                              hipStream_t stream) {
    // setup_inputs order: x, w_q, w_kv, w_out, b_out, rel_height, rel_width
    const float* x     = (const float*)d_in[0];
    const float* w_kv  = (const float*)d_in[2];
    const float* w_out = (const float*)d_in[3];
    const float* b_out = (const float*)d_in[4];
    float* W     = (float*)d_ws;            // 256*256 floats = 256 KiB
    float* means = W + 256 * 256;           // 8*36*256 floats = 288 KiB

    halo_prep_kernel<<<2048 + 128, 256, 0, stream>>>(x, w_kv, w_out, W, means);
    halo_out_kernel<<<dim3(8, 8, 8), 256, 0, stream>>>(W, means, b_out, (float*)d_out);
}

// Round 4
// 120.224 us; speedup vs baseline: 1.3521x; 1.0193x over previous
//
#include <hip/hip_runtime.h>

// HaloAttention with the lucidrains masking bug faithfully replicated:
// in-bounds keys get -FLT_MAX, so
//   * interior blocks -> uniform attention = 16x16 box-mean of v
//   * border blocks   -> attention only on zero-padded keys -> output exactly 0
// Collapse: out_block = mean16x16(x) @ (w_kv[:,512:] @ w_out) + b_out (interior),
//           0 (border). q / w_q / rel_* are dead inputs.
//
// Dispatch 1 (prep): blocks 0..511 compute 16x16 window means for 4 channel
//   planes each (x read exactly once, coalesced, via 4x4 coarse-tile sums;
//   windows start at multiples of 4). Blocks 512..639 compose W = w_kv_v @ w_out.
// Dispatch 2 (out): block = (32-channel group g, block row bi, batch b).
//   Phase 1: matvec outv[c][bj] into LDS via float4 W loads with 4-way k-split.
//   Phase 2: stream the 8x64x32 strip with fully coalesced float4 stores.

__global__ __launch_bounds__(256)
void halo_prep_kernel(const float* __restrict__ x,
                      const float* __restrict__ w_kv,
                      const float* __restrict__ w_out,
                      float* __restrict__ W,
                      float* __restrict__ means) {
    const int t = threadIdx.x;
    if (blockIdx.x < 512) {
        // ---- window means for 4 (b, c) planes ----
        const int b  = blockIdx.x >> 6;
        const int c0 = (blockIdx.x & 63) * 4;
        __shared__ float ts[4][256];  // per-plane 16x16 coarse 4x4-tile sums
        const int ti = t >> 4, tj = t & 15;
#pragma unroll
        for (int q = 0; q < 4; ++q) {
            const float* tp = x + ((size_t)(b * 256 + c0 + q)) * 4096
                                + (size_t)(ti * 4) * 64 + tj * 4;
            float s = 0.f;
#pragma unroll
            for (int r = 0; r < 4; ++r) {
                float4 a = *(const float4*)(tp + (size_t)r * 64);
                s += (a.x + a.y) + (a.z + a.w);
            }
            ts[q][t] = s;
        }
        __syncthreads();
        if (t < 144) {
            // interior block (bi,bj) = (wi+1, wj+1); window top row bi*8-4
            // -> tile row 2*bi-1, spans 4 tile rows/cols
            const int q  = t / 36;
            const int w  = t - q * 36;
            const int wi = w / 6, wj = w - wi * 6;
            const int tr = 2 * wi + 1, tc = 2 * wj + 1;
            float acc = 0.f;
#pragma unroll
            for (int di = 0; di < 4; ++di)
#pragma unroll
                for (int dj = 0; dj < 4; ++dj)
                    acc += ts[q][(tr + di) * 16 + (tc + dj)];
            means[((size_t)b * 36 + w) * 256 + (c0 + q)] = acc * (1.f / 256.f);
        }
    } else {
        // ---- compose W rows c0, c0+1: W[c][c2] = sum_j w_kv[c][512+j]*w_out[j][c2] ----
        const int c0 = (blockIdx.x - 512) * 2;
        const float* kv0 = w_kv + (size_t)c0 * 1024 + 512;
        const float* kv1 = kv0 + 1024;
        float a0 = 0.f, a1 = 0.f;
#pragma unroll 8
        for (int j = 0; j < 512; ++j) {
            const float wo = w_out[(size_t)j * 256 + t];  // coalesced over t
            a0 = fmaf(kv0[j], wo, a0);                    // kv*: wg-uniform scalar loads
            a1 = fmaf(kv1[j], wo, a1);
        }
        W[(size_t)c0 * 256 + t] = a0;
        W[((size_t)c0 + 1) * 256 + t] = a1;
    }
}

__global__ __launch_bounds__(256)
void halo_out_kernel(const float* __restrict__ W,
                     const float* __restrict__ means,
                     const float* __restrict__ b_out,
                     float* __restrict__ out) {
    const int g  = blockIdx.x;   // channel group 0..7 (32 channels)
    const int bi = blockIdx.y;   // block row 0..7
    const int b  = blockIdx.z;   // batch
    const int t  = threadIdx.x;
    const bool bi_int = (bi >= 1) & (bi <= 6);

    __shared__ float m_lds[8][256];   // means rows per bj (0 at border bj)
    __shared__ float4 psum4[256];     // [(bj*8+q)*4 + sub]
    __shared__ float outv[32 * 9];    // [c_local][bj], stride 9 avoids conflicts

    if (bi_int) {  // wg-uniform branch: barriers inside are legal
        // stage means rows (bj=1..6 real, bj=0,7 zero)
        {
            const int row = t >> 5;
            const int col0 = t & 31;
            const float* mrow = (row >= 1 && row <= 6)
                ? &means[((size_t)b * 36 + (size_t)(bi - 1) * 6 + (row - 1)) * 256]
                : nullptr;
#pragma unroll
            for (int kk = col0; kk < 256; kk += 32)
                m_lds[row][kk] = mrow ? mrow[kk] : 0.f;
        }
        __syncthreads();

        // matvec: thread (bj = t>>5, sub = (t>>3)&3, q = t&7)
        // computes partial over k in [sub*64, sub*64+64) for channels cb..cb+3
        {
            const int bj  = t >> 5;
            const int sub = (t >> 3) & 3;
            const int q   = t & 7;
            const int cb  = g * 32 + q * 4;    // 16B-aligned
            const float* mr = m_lds[bj];
            const int k0 = sub * 64;
            float4 a = make_float4(0.f, 0.f, 0.f, 0.f);
#pragma unroll 4
            for (int k = k0; k < k0 + 64; ++k) {
                const float4 w4 = *(const float4*)&W[(size_t)k * 256 + cb];
                const float mm = mr[k];
                a.x = fmaf(mm, w4.x, a.x);
                a.y = fmaf(mm, w4.y, a.y);
                a.z = fmaf(mm, w4.z, a.z);
                a.w = fmaf(mm, w4.w, a.w);
            }
            psum4[(bj * 8 + q) * 4 + sub] = a;
        }
        __syncthreads();

        // reduce 4 k-partials -> outv[c][bj], add bias, zero border bj
        {
            const int bj = t >> 5;
            const int cl = t & 31;
            const int q2 = cl >> 2, ch = cl & 3;
            const float* ps = (const float*)psum4;
            float v = 0.f;
#pragma unroll
            for (int s = 0; s < 4; ++s)
                v += ps[((bj * 8 + q2) * 4 + s) * 4 + ch];
            const bool bj_int = (bj >= 1) & (bj <= 6);
            outv[cl * 9 + bj] = bj_int ? v + b_out[g * 32 + cl] : 0.f;
        }
        __syncthreads();
    }

    // phase 2: stream the strip out[b][g*32..+32][bi*8..+8][0..64]
    // each wave writes 1 KB fully contiguous
    float* base = out + ((size_t)(b * 256 + g * 32)) * 4096 + (size_t)(bi * 8) * 64;
#pragma unroll
    for (int i = 0; i < 16; ++i) {
        const int idx = i * 256 + t;     // float4 index in the 64 KB strip
        const int cl2 = idx >> 7;        // 128 float4 per channel
        const int rem = idx & 127;       // y*16 + x4
        const int x4  = rem & 15;
        const float v = bi_int ? outv[cl2 * 9 + (x4 >> 1)] : 0.f;
        *(float4*)(base + (size_t)cl2 * 4096 + (size_t)rem * 4) = make_float4(v, v, v, v);
    }
}

extern "C" void kernel_launch(void* const* d_in, const int* in_sizes, int n_in,
                              void* d_out, int out_size, void* d_ws, size_t ws_size,
                              hipStream_t stream) {
    // setup_inputs order: x, w_q, w_kv, w_out, b_out, rel_height, rel_width
    const float* x     = (const float*)d_in[0];
    const float* w_kv  = (const float*)d_in[2];
    const float* w_out = (const float*)d_in[3];
    const float* b_out = (const float*)d_in[4];
    float* W     = (float*)d_ws;            // 256*256 floats = 256 KiB
    float* means = W + 256 * 256;           // 8*36*256 floats = 288 KiB

    halo_prep_kernel<<<512 + 128, 256, 0, stream>>>(x, w_kv, w_out, W, means);
    halo_out_kernel<<<dim3(8, 8, 8), 256, 0, stream>>>(W, means, b_out, (float*)d_out);
}